// Round 4
// baseline (1791.041 us; speedup 1.0000x reference)
//
#include <hip/hip_runtime.h>

#define BB 8
#define NN 4096
#define KK 20
constexpr float EPSV = 1e-5f;
constexpr float SLOPE = 0.2f;

typedef __bf16 bfrag __attribute__((ext_vector_type(8)));
typedef float floatx4 __attribute__((ext_vector_type(4)));
typedef unsigned short us8 __attribute__((ext_vector_type(8)));

__device__ __forceinline__ float lrelu(float v) { return v >= 0.f ? v : SLOPE * v; }

__device__ __forceinline__ unsigned short bf16rn(float f) {
    unsigned int u = __float_as_uint(f);
    return (unsigned short)((u + 0x7FFFu + ((u >> 16) & 1u)) >> 16);
}
__device__ __forceinline__ float bf16up(unsigned short h) {
    return __uint_as_float(((unsigned int)h) << 16);
}

// async global->LDS 16B copy: dest = lds_base + lane*16
__device__ __forceinline__ void gl2lds16(const void* g, void* l) {
    __builtin_amdgcn_global_load_lds(
        (const __attribute__((address_space(1))) unsigned int*)g,
        (__attribute__((address_space(3))) unsigned int*)l, 16, 0, 0);
}

__global__ void zero_kernel(float* p, int n) {
    int i = blockIdx.x * 256 + threadIdx.x;
    if (i < n) p[i] = 0.f;
}

// 0.5*||x_n||^2 per point (exact fp32). grid (NN/256, BB), block 256.
template<int C>
__global__ void halfnorm_kernel(const float* __restrict__ src, float* __restrict__ hng) {
    int n = blockIdx.x * 256 + threadIdx.x;
    int b = blockIdx.y;
    float s = 0.f;
    #pragma unroll
    for (int c = 0; c < C; c++) { float v = src[(b * C + c) * NN + n]; s += v * v; }
    hng[b * NN + n] = 0.5f * s;
}

// ---- pack kernels: hi/lo bf16 rows [hi(C)|lo(C)], 16B chunks XOR-swizzled by row ----
// C>=32: row = 2C shorts = C/4 chunks; phys chunk = j ^ (n & (C/4-1)).
template<int C>
__global__ void pack_kernel(const float* __restrict__ src, unsigned short* __restrict__ pk) {
    constexpr int NCH = C / 4;
    int i = blockIdx.x * 256 + threadIdx.x;    // over NN*NCH
    int b = blockIdx.y;
    int n = i / NCH, j = i % NCH;
    us8 v;
    if (j < C / 8) {
        int c0 = j * 8;
        #pragma unroll
        for (int cc = 0; cc < 8; cc++)
            v[cc] = bf16rn(src[(b * C + c0 + cc) * NN + n]);
    } else {
        int c0 = (j - C / 8) * 8;
        #pragma unroll
        for (int cc = 0; cc < 8; cc++) {
            float f = src[(b * C + c0 + cc) * NN + n];
            unsigned short h = bf16rn(f);
            v[cc] = bf16rn(f - bf16up(h));
        }
    }
    int phys = j ^ (n & (NCH - 1));
    *(us8*)(pk + ((size_t)(b * NN + n) * NCH + phys) * 8) = v;
}

// C=3: 32-short rows. A-row: [h3 l3 h3 l3 | 0..], B-row: [h3 l3 l3 h3 | 0..].
__global__ void pack3_kernel(const float* __restrict__ src,
                             unsigned short* __restrict__ pa, unsigned short* __restrict__ pb) {
    int n = blockIdx.x * 256 + threadIdx.x;
    int b = blockIdx.y;
    unsigned short h[3], l[3];
    #pragma unroll
    for (int c = 0; c < 3; c++) {
        float f = src[(b * 3 + c) * NN + n];
        h[c] = bf16rn(f);
        l[c] = bf16rn(f - bf16up(h[c]));
    }
    unsigned short A[32], B[32];
    #pragma unroll
    for (int k = 0; k < 32; k++) { A[k] = 0; B[k] = 0; }
    #pragma unroll
    for (int c = 0; c < 3; c++) {
        A[c] = h[c];     A[3 + c] = l[c];  A[6 + c] = h[c];  A[9 + c] = l[c];
        B[c] = h[c];     B[3 + c] = l[c];  B[6 + c] = l[c];  B[9 + c] = h[c];
    }
    size_t base = (size_t)(b * NN + n) * 32;
    #pragma unroll
    for (int j = 0; j < 4; j++) {
        int phys = j ^ (n & 3);
        us8 va, vb;
        #pragma unroll
        for (int t = 0; t < 8; t++) { va[t] = A[j * 8 + t]; vb[t] = B[j * 8 + t]; }
        *(us8*)(pa + base + phys * 8) = va;
        *(us8*)(pb + base + phys * 8) = vb;
    }
}

// ---------------- kNN: MFMA tiles from pre-packed bf16, parallel drain ----------------
// grid (NN/64, BB), block 256 (4 waves). Block tile: 64 queries x 128 candidates/chunk,
// 32 chunks. Wave w: rows wr=(w>>1)*32, cols wc=(w&1)*64 (8 16x16 acc tiles).
// Query q's top-20 lives in registers of wave q/16, lane q%16 (parallel drain).
template<int C>
__global__ __launch_bounds__(256) void knn_kernel(const unsigned short* __restrict__ pq,
                                                  const unsigned short* __restrict__ pc,
                                                  const float* __restrict__ hng,
                                                  int* __restrict__ idx) {
    constexpr int RS = (C == 3) ? 32 : 2 * C;   // shorts per row
    constexpr int NCHR = RS / 8;                // 16B chunks per row
    constexpr int SWM = NCHR - 1;
    __shared__ unsigned short qpack[64 * RS];
    __shared__ unsigned short cpack[128 * RS];
    __shared__ float hn[128];
    __shared__ float pv[64 * 33];
    __shared__ unsigned short pidx[64 * 34];
    __shared__ float tau[64];
    __shared__ int   cnt[64];

    const int b = blockIdx.y;
    const int q0 = blockIdx.x * 64;
    const int tid = threadIdx.x;
    const int lane = tid & 63;
    const int wv = tid >> 6;
    const int fl = lane & 15;
    const int fq = lane >> 4;
    const int wr = (wv >> 1) * 32;
    const int wc = (wv & 1) * 64;

    // stage queries via async DMA (1KB per wave-call)
    {
        const char* gq = (const char*)(pq + (size_t)(b * NN + q0) * RS);
        constexpr int PQW = (64 * RS * 2 / 1024) / 4;
        #pragma unroll
        for (int t = 0; t < PQW; t++) {
            int seg = wv * PQW + t;
            gl2lds16(gq + seg * 1024 + lane * 16, (char*)qpack + seg * 1024);
        }
    }
    if (tid < 64) { tau[tid] = -3.4e38f; cnt[tid] = 0; }

    float tv[20]; int ti[20];
    #pragma unroll
    for (int k = 0; k < 20; k++) { tv[k] = -3.4e38f; ti[k] = 0; }

    for (int ch = 0; ch < 32; ch++) {
        const int m0 = ch * 128;
        {
            const char* gc = (const char*)(pc + (size_t)(b * NN + m0) * RS);
            constexpr int PCW = (128 * RS * 2 / 1024) / 4;
            #pragma unroll
            for (int t = 0; t < PCW; t++) {
                int seg = wv * PCW + t;
                gl2lds16(gc + seg * 1024 + lane * 16, (char*)cpack + seg * 1024);
            }
        }
        if (tid < 128) hn[tid] = hng[b * NN + m0 + tid];
        __syncthreads();

        floatx4 acc[2][4];
        #pragma unroll
        for (int r2 = 0; r2 < 2; r2++)
            #pragma unroll
            for (int c2 = 0; c2 < 4; c2++)
                acc[r2][c2] = (floatx4)(0.f);

        if constexpr (C == 3) {
            bfrag a[2];
            #pragma unroll
            for (int r2 = 0; r2 < 2; r2++) {
                int row = wr + r2 * 16 + fl;
                a[r2] = *(const bfrag*)(qpack + row * RS + (fq ^ (row & SWM)) * 8);
            }
            #pragma unroll
            for (int c2 = 0; c2 < 4; c2++) {
                int row = wc + c2 * 16 + fl;
                bfrag bm = *(const bfrag*)(cpack + row * RS + (fq ^ (row & SWM)) * 8);
                #pragma unroll
                for (int r2 = 0; r2 < 2; r2++)
                    acc[r2][c2] = __builtin_amdgcn_mfma_f32_16x16x32_bf16(a[r2], bm, acc[r2][c2], 0, 0, 0);
            }
        } else {
            #pragma unroll
            for (int kk = 0; kk < C / 32; kk++) {
                bfrag ah[2], al[2], bh[4], bl[4];
                #pragma unroll
                for (int r2 = 0; r2 < 2; r2++) {
                    int row = wr + r2 * 16 + fl;
                    ah[r2] = *(const bfrag*)(qpack + row * RS + ((kk * 4 + fq) ^ (row & SWM)) * 8);
                    al[r2] = *(const bfrag*)(qpack + row * RS + ((C / 8 + kk * 4 + fq) ^ (row & SWM)) * 8);
                }
                #pragma unroll
                for (int c2 = 0; c2 < 4; c2++) {
                    int row = wc + c2 * 16 + fl;
                    bh[c2] = *(const bfrag*)(cpack + row * RS + ((kk * 4 + fq) ^ (row & SWM)) * 8);
                    bl[c2] = *(const bfrag*)(cpack + row * RS + ((C / 8 + kk * 4 + fq) ^ (row & SWM)) * 8);
                }
                #pragma unroll
                for (int r2 = 0; r2 < 2; r2++)
                    #pragma unroll
                    for (int c2 = 0; c2 < 4; c2++) {
                        acc[r2][c2] = __builtin_amdgcn_mfma_f32_16x16x32_bf16(ah[r2], bh[c2], acc[r2][c2], 0, 0, 0);
                        acc[r2][c2] = __builtin_amdgcn_mfma_f32_16x16x32_bf16(ah[r2], bl[c2], acc[r2][c2], 0, 0, 0);
                        acc[r2][c2] = __builtin_amdgcn_mfma_f32_16x16x32_bf16(al[r2], bh[c2], acc[r2][c2], 0, 0, 0);
                        acc[r2][c2] = __builtin_amdgcn_mfma_f32_16x16x32_bf16(al[r2], bl[c2], acc[r2][c2], 0, 0, 0);
                    }
            }
        }

        auto filter_one = [&](int c2) {
            float hnv = hn[wc + c2 * 16 + fl];
            #pragma unroll
            for (int r2 = 0; r2 < 2; r2++) {
                const float* tp = &tau[wr + r2 * 16 + fq * 4];
                float t0 = tp[0], t1 = tp[1], t2 = tp[2], t3 = tp[3];
                float ta[4] = {t0, t1, t2, t3};
                #pragma unroll
                for (int reg = 0; reg < 4; reg++) {
                    float s = acc[r2][c2][reg] - hnv;
                    if (s > ta[reg]) {
                        int q = wr + r2 * 16 + fq * 4 + reg;
                        int p = atomicAdd(&cnt[q], 1);
                        if (p < 32) {
                            pv[q * 33 + p] = s;
                            pidx[q * 34 + p] = (unsigned short)(m0 + wc + c2 * 16 + fl);
                        }
                    }
                }
            }
        };
        auto drain = [&]() {
            if (lane < 16) {
                int qd = wv * 16 + lane;
                int n = cnt[qd]; if (n > 32) n = 32;
                for (int t = 0; t < n; t++) {
                    float v = pv[qd * 33 + t];
                    if (v > tv[0]) {
                        tv[0] = v; ti[0] = (int)pidx[qd * 34 + t];
                        #pragma unroll
                        for (int j = 0; j < 19; j++) {
                            if (tv[j] > tv[j + 1]) {
                                float a = tv[j]; tv[j] = tv[j + 1]; tv[j + 1] = a;
                                int bi = ti[j]; ti[j] = ti[j + 1]; ti[j + 1] = bi;
                            }
                        }
                    }
                }
                cnt[qd] = 0;
                tau[qd] = tv[0];
            }
        };

        if (ch == 0) {
            // tau=-inf: bound inserts per drain to 32 (one c2 strip at a time)
            #pragma unroll
            for (int ph = 0; ph < 4; ph++) {
                filter_one(ph);
                __syncthreads();
                drain();
                __syncthreads();
            }
        } else {
            #pragma unroll
            for (int c2 = 0; c2 < 4; c2++) filter_one(c2);
            __syncthreads();
            drain();
        }
    }

    if (lane < 16) {
        int q = q0 + wv * 16 + lane;
        #pragma unroll
        for (int k = 0; k < 20; k++)
            idx[(b * NN + q) * KK + k] = ti[k];   // order irrelevant downstream
    }
}

// ---------------- conv precompute: G = Wd*src, H = (Wc-Wd)*src ----------------
template<int COUT>
__global__ void precompute_kernel(const float* __restrict__ src, int C,
                                  const float* __restrict__ w, int CIN, int wd_off, int wc_off,
                                  float* __restrict__ G, float* __restrict__ H,
                                  int initG, int initH) {
    constexpr int MY = 256 / COUT;
    extern __shared__ float lds[];
    float* wd = lds;
    float* wc = lds + C * COUT;
    const int b = blockIdx.y;
    const int tid = threadIdx.y * COUT + threadIdx.x;
    for (int i = tid; i < C * COUT; i += 256) {
        int c = i / COUT, o = i % COUT;
        float a  = w[o * CIN + wd_off + c];
        float cc = w[o * CIN + wc_off + c];
        wd[i] = a;
        wc[i] = cc - a;
    }
    __syncthreads();
    const int o = threadIdx.x;
    for (int it = 0; it < COUT / 4; it++) {
        int m = blockIdx.x * 64 + it * MY + threadIdx.y;
        float g = 0.f, h = 0.f;
        for (int c = 0; c < C; c++) {
            float s = src[(b * C + c) * NN + m];
            g += wd[c * COUT + o] * s;
            h += wc[c * COUT + o] * s;
        }
        int gi = (b * NN + m) * COUT + o;
        if (initG) G[gi] = g; else G[gi] += g;
        if (initH) H[gi] = h; else H[gi] += h;
    }
}

// ---------------- conv stats + per-(b,n,o) min/max over k ----------------
template<int COUT, int GROUPS>
__global__ void conv_stats_kernel(const float* __restrict__ G1, const int* __restrict__ idx1,
                                  const float* __restrict__ G2, const int* __restrict__ idx2,
                                  const float* __restrict__ H, float* __restrict__ stats,
                                  float* __restrict__ MaxY, float* __restrict__ MinY) {
    constexpr int NY = 256 / COUT;
    const int b = blockIdx.y;
    const int o = threadIdx.x;
    const int n = blockIdx.x * NY + threadIdx.y;
    const int base = b * NN + n;
    const float h = H[base * COUT + o];
    float s1 = 0.f, s2 = 0.f;
    float gx = -3.4e38f, gn = 3.4e38f;
    #pragma unroll
    for (int k = 0; k < KK; k++) {
        int i1 = idx1[base * KK + k];
        float g = G1[(b * NN + i1) * COUT + o];
        if (GROUPS == 2) {
            int i2 = idx2[base * KK + k];
            g += G2[(b * NN + i2) * COUT + o];
        }
        float y = g + h;
        s1 += y;
        s2 += y * y;
        gx = fmaxf(gx, g);
        gn = fminf(gn, g);
    }
    MaxY[base * COUT + o] = gx + h;
    MinY[base * COUT + o] = gn + h;

    __shared__ float ls[2 * COUT];
    if (threadIdx.y == 0) { ls[o] = 0.f; ls[COUT + o] = 0.f; }
    __syncthreads();
    atomicAdd(&ls[o], s1);
    atomicAdd(&ls[COUT + o], s2);
    __syncthreads();
    if (threadIdx.y == 0) {
        atomicAdd(&stats[o], ls[o]);
        atomicAdd(&stats[64 + o], ls[COUT + o]);
    }
}

__global__ void finalize_kernel(const float* __restrict__ g, const float* __restrict__ bb,
                                float* __restrict__ stats, int cout, float invP) {
    int o = threadIdx.x;
    if (o >= cout) return;
    float mu  = stats[o] * invP;
    float var = stats[64 + o] * invP - mu * mu;
    float sc  = g[o] * rsqrtf(var + EPSV);
    stats[128 + o] = sc;
    stats[192 + o] = bb[o] - mu * sc;
}

__global__ void apply_kernel(const float* __restrict__ MaxY, const float* __restrict__ MinY,
                             const float* __restrict__ stats, float* __restrict__ out, int cout) {
    int e = blockIdx.x * 256 + threadIdx.x;
    int total = BB * cout * NN;
    if (e >= total) return;
    int n = e & (NN - 1);
    int o = (e >> 12) % cout;
    int b = e / (NN * cout);
    float sc = stats[128 + o], sh = stats[192 + o];
    int si = (b * NN + n) * cout + o;
    float v = (sc >= 0.f) ? MaxY[si] : MinY[si];
    out[e] = lrelu(sc * v + sh);
}

__global__ void mean_kernel(const float* __restrict__ xd1, const float* __restrict__ xd2,
                            float* __restrict__ hsum) {
    __shared__ float bins[128];
    const int tid = threadIdx.x;
    if (tid < 128) bins[tid] = 0.f;
    __syncthreads();
    const int half = BB * 64 * NN;
    const int stride = gridDim.x * 256;
    for (int e = blockIdx.x * 256 + tid; e < half; e += stride)
        atomicAdd(&bins[e & 127], xd1[e]);
    for (int e = blockIdx.x * 256 + tid; e < half; e += stride)
        atomicAdd(&bins[e & 127], xd2[e]);
    __syncthreads();
    if (tid < 128) atomicAdd(&hsum[tid], bins[tid]);
}

__global__ void head_kernel(const float* __restrict__ hsum,
                            const float* __restrict__ W2d, const float* __restrict__ b2d,
                            const float* __restrict__ W3d, const float* __restrict__ b3d,
                            const float* __restrict__ W4d, const float* __restrict__ b4d,
                            float* __restrict__ out) {
    __shared__ float h[128], t1[128], t2[64];
    const int t = threadIdx.x;
    h[t] = hsum[t] * (1.f / 32768.f);
    __syncthreads();
    float a = b2d[t];
    for (int j = 0; j < 128; j++) a += W2d[t * 128 + j] * h[j];
    t1[t] = lrelu(a);
    __syncthreads();
    if (t < 64) {
        float a2 = b3d[t];
        for (int j = 0; j < 128; j++) a2 += W3d[t * 128 + j] * t1[j];
        t2[t] = lrelu(a2);
    }
    __syncthreads();
    if (t < 11) {
        float a3 = b4d[t];
        for (int j = 0; j < 64; j++) a3 += W4d[t * 64 + j] * t2[j];
        out[t] = lrelu(a3);
    }
}

extern "C" void kernel_launch(void* const* d_in, const int* in_sizes, int n_in,
                              void* d_out, int out_size, void* d_ws, size_t ws_size,
                              hipStream_t stream) {
    const float* x   = (const float*)d_in[0];
    const float* w1  = (const float*)d_in[1];
    const float* g1  = (const float*)d_in[2];
    const float* b1  = (const float*)d_in[3];
    const float* w2  = (const float*)d_in[4];
    const float* g2  = (const float*)d_in[5];
    const float* b2  = (const float*)d_in[6];
    const float* wd1 = (const float*)d_in[7];
    const float* gd1 = (const float*)d_in[8];
    const float* bd1 = (const float*)d_in[9];
    const float* wd2 = (const float*)d_in[10];
    const float* gd2 = (const float*)d_in[11];
    const float* bd2 = (const float*)d_in[12];
    const float* W2d = (const float*)d_in[13];
    const float* b2d = (const float*)d_in[14];
    const float* W3d = (const float*)d_in[15];
    const float* b3d = (const float*)d_in[16];
    const float* W4d = (const float*)d_in[17];
    const float* b4d = (const float*)d_in[18];
    float* out = (float*)d_out;

    char* ws = (char*)d_ws;
    size_t off = 0;
    auto alloc = [&](size_t bytes) { char* p = ws + off; off += (bytes + 255) & ~size_t(255); return p; };
    int*   idx1  = (int*)  alloc(BB * NN * KK * 4);
    int*   idx2  = (int*)  alloc(BB * NN * KK * 4);
    int*   idx3  = (int*)  alloc(BB * NN * KK * 4);
    float* x1m   = (float*)alloc(BB * 32 * NN * 4);
    float* x2m   = (float*)alloc(BB * 64 * NN * 4);
    float* xd1   = (float*)alloc(BB * 64 * NN * 4);
    float* xd2   = (float*)alloc(BB * 64 * NN * 4);
    float* G1    = (float*)alloc((size_t)BB * NN * 64 * 4);
    float* G2    = (float*)alloc((size_t)BB * NN * 64 * 4);
    float* H     = (float*)alloc((size_t)BB * NN * 64 * 4);
    float* MaxY  = (float*)alloc((size_t)BB * NN * 64 * 4);
    float* MinY  = (float*)alloc((size_t)BB * NN * 64 * 4);
    float* stats = (float*)alloc(256 * 4);
    float* hsum  = (float*)alloc(128 * 4);
    float* hng   = (float*)alloc(BB * NN * 4);
    unsigned short* pa3  = (unsigned short*)alloc((size_t)BB * NN * 32 * 2);
    unsigned short* pb3  = (unsigned short*)alloc((size_t)BB * NN * 32 * 2);
    unsigned short* pk32 = (unsigned short*)alloc((size_t)BB * NN * 64 * 2);
    unsigned short* pk64 = (unsigned short*)alloc((size_t)BB * NN * 128 * 2);

    const float invP = 1.f / (float)(BB * NN * KK);
    const dim3 knn_grid(NN / 64, BB);
    const dim3 hn_grid(NN / 256, BB);

    zero_kernel<<<1, 256, 0, stream>>>(hsum, 128);

    // --- kNN on x (C=3) ---
    halfnorm_kernel<3><<<hn_grid, 256, 0, stream>>>(x, hng);
    pack3_kernel<<<dim3(NN / 256, BB), 256, 0, stream>>>(x, pa3, pb3);
    knn_kernel<3><<<knn_grid, 256, 0, stream>>>(pa3, pb3, hng, idx1);

    // --- conv1: Cout=32, group (x, idx1, C=3), w1 CIN=6 ---
    zero_kernel<<<1, 256, 0, stream>>>(stats, 128);
    precompute_kernel<32><<<dim3(NN / 64, BB), dim3(32, 8), 2 * 3 * 32 * 4, stream>>>(
        x, 3, w1, 6, 0, 3, G1, H, 1, 1);
    conv_stats_kernel<32, 1><<<dim3(NN / 8, BB), dim3(32, 8), 0, stream>>>(
        G1, idx1, nullptr, nullptr, H, stats, MaxY, MinY);
    finalize_kernel<<<1, 64, 0, stream>>>(g1, b1, stats, 32, invP);
    apply_kernel<<<(BB * 32 * NN + 255) / 256, 256, 0, stream>>>(MaxY, MinY, stats, x1m, 32);

    // --- kNN on x1_max (C=32) ---
    halfnorm_kernel<32><<<hn_grid, 256, 0, stream>>>(x1m, hng);
    pack_kernel<32><<<dim3(NN * 8 / 256, BB), 256, 0, stream>>>(x1m, pk32);
    knn_kernel<32><<<knn_grid, 256, 0, stream>>>(pk32, pk32, hng, idx2);

    // --- conv2: Cout=64, groups (x, idx1, 3) + (x1m, idx2, 32), w2 CIN=70 ---
    zero_kernel<<<1, 256, 0, stream>>>(stats, 128);
    precompute_kernel<64><<<dim3(NN / 64, BB), dim3(64, 4), 2 * 3 * 64 * 4, stream>>>(
        x, 3, w2, 70, 0, 3, G1, H, 1, 1);
    precompute_kernel<64><<<dim3(NN / 64, BB), dim3(64, 4), 2 * 32 * 64 * 4, stream>>>(
        x1m, 32, w2, 70, 6, 38, G2, H, 1, 0);
    conv_stats_kernel<64, 2><<<dim3(NN / 4, BB), dim3(64, 4), 0, stream>>>(
        G1, idx1, G2, idx2, H, stats, MaxY, MinY);
    finalize_kernel<<<1, 64, 0, stream>>>(g2, b2, stats, 64, invP);
    apply_kernel<<<(BB * 64 * NN + 255) / 256, 256, 0, stream>>>(MaxY, MinY, stats, x2m, 64);

    // --- convd1: Cout=64, group (x1m, idx2, 32), wd1 CIN=64 ---
    zero_kernel<<<1, 256, 0, stream>>>(stats, 128);
    precompute_kernel<64><<<dim3(NN / 64, BB), dim3(64, 4), 2 * 32 * 64 * 4, stream>>>(
        x1m, 32, wd1, 64, 0, 32, G1, H, 1, 1);
    conv_stats_kernel<64, 1><<<dim3(NN / 4, BB), dim3(64, 4), 0, stream>>>(
        G1, idx2, nullptr, nullptr, H, stats, MaxY, MinY);
    finalize_kernel<<<1, 64, 0, stream>>>(gd1, bd1, stats, 64, invP);
    apply_kernel<<<(BB * 64 * NN + 255) / 256, 256, 0, stream>>>(MaxY, MinY, stats, xd1, 64);

    // --- kNN on x2_max (C=64) ---
    halfnorm_kernel<64><<<hn_grid, 256, 0, stream>>>(x2m, hng);
    pack_kernel<64><<<dim3(NN * 16 / 256, BB), 256, 0, stream>>>(x2m, pk64);
    knn_kernel<64><<<knn_grid, 256, 0, stream>>>(pk64, pk64, hng, idx3);

    // --- convd2: Cout=64, group (x2m, idx3, 64), wd2 CIN=128 ---
    zero_kernel<<<1, 256, 0, stream>>>(stats, 128);
    precompute_kernel<64><<<dim3(NN / 64, BB), dim3(64, 4), 2 * 64 * 64 * 4, stream>>>(
        x2m, 64, wd2, 128, 0, 64, G1, H, 1, 1);
    conv_stats_kernel<64, 1><<<dim3(NN / 4, BB), dim3(64, 4), 0, stream>>>(
        G1, idx3, nullptr, nullptr, H, stats, MaxY, MinY);
    finalize_kernel<<<1, 64, 0, stream>>>(gd2, bd2, stats, 64, invP);
    apply_kernel<<<(BB * 64 * NN + 255) / 256, 256, 0, stream>>>(MaxY, MinY, stats, xd2, 64);

    // --- global mean + MLP head ---
    mean_kernel<<<1024, 256, 0, stream>>>(xd1, xd2, hsum);
    head_kernel<<<1, 128, 0, stream>>>(hsum, W2d, b2d, W3d, b3d, W4d, b4d, out);
}